// Round 1
// 238.980 us; speedup vs baseline: 1.0627x; 1.0627x over previous
//
#include <hip/hip_runtime.h>
#include <math.h>

// Problem constants (fixed by setup_inputs)
#define BB 8
#define TT 128
#define CC 1024
#define HH 16
#define DD 64
#define CAP 2048
#define NSPLIT 4   // flash-decoding S-splits for attention

typedef __attribute__((ext_vector_type(8))) short short8;
typedef __attribute__((ext_vector_type(4))) short short4v;
typedef __attribute__((ext_vector_type(4))) float float4v;
typedef _Float16 half8 __attribute__((ext_vector_type(8)));
typedef _Float16 half4v __attribute__((ext_vector_type(4)));

__device__ __forceinline__ short f2bf(float x) {
    union { float f; unsigned u; } un; un.f = x;
    unsigned r = (un.u + 0x7FFF + ((un.u >> 16) & 1)) >> 16;
    return (short)r;
}
__device__ __forceinline__ float bf2f(unsigned short h) {
    union { unsigned u; float f; } un; un.u = ((unsigned)h) << 16;
    return un.f;
}

// ---------------- fused split: x -> fp16 hi/lo; w_in, w_out -> fp16 ----------------
__global__ __launch_bounds__(256) void split_all(const float* __restrict__ x,
                                                 const float* __restrict__ w_in,
                                                 const float* __restrict__ w_out,
                                                 _Float16* __restrict__ xhi,
                                                 _Float16* __restrict__ xlo,
                                                 _Float16* __restrict__ wh,
                                                 _Float16* __restrict__ woh) {
    size_t i = ((size_t)blockIdx.x * 256 + threadIdx.x) * 4;
    if (i < (size_t)1048576) {
        float4 f = *(const float4*)(x + i);
        half4v h, l;
        h.x = (_Float16)f.x; l.x = (_Float16)(f.x - (float)h.x);
        h.y = (_Float16)f.y; l.y = (_Float16)(f.y - (float)h.y);
        h.z = (_Float16)f.z; l.z = (_Float16)(f.z - (float)h.z);
        h.w = (_Float16)f.w; l.w = (_Float16)(f.w - (float)h.w);
        *(half4v*)(xhi + i) = h;
        *(half4v*)(xlo + i) = l;
    } else if (i < (size_t)4194304) {
        size_t off = i - 1048576;
        float4 f = *(const float4*)(w_in + off);
        half4v h;
        h.x = (_Float16)f.x; h.y = (_Float16)f.y; h.z = (_Float16)f.z; h.w = (_Float16)f.w;
        *(half4v*)(wh + off) = h;
    } else {
        size_t off = i - 4194304;
        float4 f = *(const float4*)(w_out + off);
        half4v h;
        h.x = (_Float16)f.x; h.y = (_Float16)f.y; h.z = (_Float16)f.z; h.w = (_Float16)f.w;
        *(half4v*)(woh + off) = h;
    }
}

// ---------------- fp16 2-term GEMM: C[M,N] = (Ahi+Alo)[M,K] * B[N,K]^T ----------------
template <int ROWS>
__device__ __forceinline__ void stage_glds(const unsigned short* __restrict__ src,
                                           unsigned short* lds, int K, int wv, int lane) {
#pragma unroll
    for (int c = wv; c < ROWS / 16; c += 4) {
        int row = c * 16 + (lane >> 2);
        int g = lane & 3;
        const unsigned short* ga = src + (size_t)row * K + g * 8;
        unsigned short* la = lds + c * 512 + lane * 8;
        __builtin_amdgcn_global_load_lds((__attribute__((address_space(1))) const unsigned short*)ga,
                                         (__attribute__((address_space(3))) unsigned short*)la,
                                         16, 0, 0);
    }
}

template <int MT, int NT>
__global__ __launch_bounds__(256) void gemm_f16x2(const _Float16* __restrict__ Ahi,
                                                  const _Float16* __restrict__ Alo,
                                                  const _Float16* __restrict__ Bh,
                                                  float* __restrict__ C, int M, int N, int K) {
    constexpr int BM = 2 * MT * 16, BN = 2 * NT * 16;
    __shared__ __align__(16) _Float16 As_h[BM * 32];
    __shared__ __align__(16) _Float16 As_l[BM * 32];
    __shared__ __align__(16) _Float16 Bs[BN * 32];

    int tid = threadIdx.x;
    int lane = tid & 63, wv = tid >> 6;
    int wr = wv >> 1, wc = wv & 1;
    int quad = lane >> 4, lq = lane & 15;
    int m0 = blockIdx.y * BM, n0 = blockIdx.x * BN;

    float4v acc[MT][NT];
#pragma unroll
    for (int mt = 0; mt < MT; ++mt)
#pragma unroll
        for (int nt = 0; nt < NT; ++nt) acc[mt][nt] = (float4v){0.f, 0.f, 0.f, 0.f};

    const unsigned short* a_h = (const unsigned short*)(Ahi + (size_t)m0 * K);
    const unsigned short* a_l = (const unsigned short*)(Alo + (size_t)m0 * K);
    const unsigned short* b_h = (const unsigned short*)(Bh + (size_t)n0 * K);

    for (int k0 = 0; k0 < K; k0 += 32) {
        __syncthreads();
        stage_glds<BM>(a_h + k0, (unsigned short*)As_h, K, wv, lane);
        stage_glds<BM>(a_l + k0, (unsigned short*)As_l, K, wv, lane);
        stage_glds<BN>(b_h + k0, (unsigned short*)Bs, K, wv, lane);
        __syncthreads();

        half8 ah[MT], al[MT];
#pragma unroll
        for (int mt = 0; mt < MT; ++mt) {
            int row = wr * MT * 16 + mt * 16 + lq;
            ah[mt] = *(const half8*)&As_h[row * 32 + quad * 8];
            al[mt] = *(const half8*)&As_l[row * 32 + quad * 8];
        }
#pragma unroll
        for (int nt = 0; nt < NT; ++nt) {
            int row = wc * NT * 16 + nt * 16 + lq;
            half8 bh = *(const half8*)&Bs[row * 32 + quad * 8];
#pragma unroll
            for (int mt = 0; mt < MT; ++mt) {
                float4v c = acc[mt][nt];
                c = __builtin_amdgcn_mfma_f32_16x16x32_f16(ah[mt], bh, c, 0, 0, 0);
                c = __builtin_amdgcn_mfma_f32_16x16x32_f16(al[mt], bh, c, 0, 0, 0);
                acc[mt][nt] = c;
            }
        }
    }

#pragma unroll
    for (int mt = 0; mt < MT; ++mt)
#pragma unroll
        for (int nt = 0; nt < NT; ++nt) {
            int n = n0 + wc * NT * 16 + nt * 16 + lq;
#pragma unroll
            for (int r = 0; r < 4; ++r) {
                int m = m0 + wr * MT * 16 + mt * 16 + quad * 4 + r;
                C[(size_t)m * N + n] = acc[mt][nt][r];
            }
        }
}

// ---------------- RoPE + ring-buffer scatter; q emitted as bf16 ----------------
__global__ __launch_bounds__(256) void rope_scatter(const float* __restrict__ qkv,
                                                    unsigned short* __restrict__ q_bf,
                                                    float* __restrict__ cache_k,
                                                    float* __restrict__ cache_v,
                                                    const int* __restrict__ end_offset) {
    int gid = blockIdx.x * 256 + threadIdx.x;
    int j = gid & 31;
    int h = (gid >> 5) & 15;
    int t = (gid >> 9) & 127;
    int b = gid >> 16;

    int ts = end_offset[b] + t;
    int slot = ts & (CAP - 1);

    float freq = expf(-0.28782313662425574f * (float)j);
    float ang = (float)ts * freq;
    float s, c;
    sincosf(ang, &s, &c);

    const float* base = qkv + (size_t)(b * TT + t) * (3 * CC);
    int col = h * DD + 2 * j;
    float2 qv = *(const float2*)&base[col];
    float2 kv = *(const float2*)&base[CC + col];
    float2 vv = *(const float2*)&base[2 * CC + col];

    float qr = qv.x * c - qv.y * s;
    float qi = qv.x * s + qv.y * c;
    float kr = kv.x * c - kv.y * s;
    float ki = kv.x * s + kv.y * c;

    size_t qo = ((size_t)(b * HH + h) * TT + t) * DD + 2 * j;
    ushort2 qp;
    qp.x = (unsigned short)f2bf(qr);
    qp.y = (unsigned short)f2bf(qi);
    *(ushort2*)&q_bf[qo] = qp;
    size_t ko = ((size_t)(b * HH + h) * CAP + slot) * DD + 2 * j;
    *(float2*)&cache_k[ko] = make_float2(kr, ki);
    *(float2*)&cache_v[ko] = vv;
}

// ---------------- MFMA bf16 flash attention, flash-decoding split over S ----------
// grid (hb=128, qc2=2, sid=NSPLIT), block 256 = 4 waves. Each block handles a
// contiguous quarter of the KV-tile range and writes UNNORMALIZED partials
// (m, l, acc) to workspace; attn_combine merges them.
// Numerics: running max m initialized to 0, masked scores = -1e30 so that a
// fully-masked sub-range yields exactly l=0/acc=0 (safe for the combine).
__global__ __launch_bounds__(256) void attn_mfma(const unsigned short* __restrict__ qb,
                                                 const float* __restrict__ ck,
                                                 const float* __restrict__ cv,
                                                 const int* __restrict__ endo,
                                                 const unsigned char* __restrict__ emb,
                                                 const int* __restrict__ emi,
                                                 float* __restrict__ pacc012,
                                                 float* __restrict__ pacc3,
                                                 float* __restrict__ pml) {
    __shared__ __align__(16) short k_s[64 * 72];      // [s][d] bf16, stride 72
    __shared__ __align__(16) short v_t[64 * 64];      // [d][s] bf16, XOR-granule swizzle
    __shared__ __align__(16) short p_s[4][16 * 72];   // per-wave P [q][s]
    __shared__ float stat_s[4][16];                   // per-wave alpha

    int tid = threadIdx.x;
    int lane = tid & 63, wv = tid >> 6;
    int quad = lane >> 4, lq = lane & 15;
    int hb = blockIdx.x;
    int h = hb & 15, b = hb >> 4;
    int qc2 = blockIdx.y;
    int sid = blockIdx.z;
    int qrow = qc2 * 64 + wv * 16 + lq;

    int end0 = endo[b];
    int em = (emb[b] != 0) || (emi[b] != 0);
    int last = end0 + TT - 1;
    int end_index = last & (CAP - 1);
    int new_end = em ? (end0 + TT) : end0;
    int se = new_end < CAP ? new_end : CAP;
    int ntiles = (se + 63) >> 6;
    int tps = (ntiles + NSPLIT - 1) / NSPLIT;
    int t0 = sid * tps;
    int t1 = t0 + tps < ntiles ? t0 + tps : ntiles;

    const unsigned short* qrp = qb + ((size_t)(b * HH + h) * TT + qrow) * DD;
    short8 aq0 = *(const short8*)(qrp + quad * 8);
    short8 aq1 = *(const short8*)(qrp + 32 + quad * 8);

    const float* kg = ck + (size_t)(b * HH + h) * CAP * DD;
    const float* vg = cv + (size_t)(b * HH + h) * CAP * DD;

    int k_row = tid >> 4, k_f4 = tid & 15;   // K: 4 float4/thread (rows tid>>4 + 16*i)
    float4 kreg[4];
    float vreg[2][8];                        // V: granules {wv, wv+4}, lane = d column

    float m[4], l[4];
#pragma unroll
    for (int r = 0; r < 4; ++r) { m[r] = 0.0f; l[r] = 0.f; }   // max floored at 0
    float4v acc[4];
#pragma unroll
    for (int mt = 0; mt < 4; ++mt) acc[mt] = (float4v){0.f, 0.f, 0.f, 0.f};

    if (t0 < t1) {
        int sb = t0 * 64;
#pragma unroll
        for (int i = 0; i < 4; ++i)
            kreg[i] = *(const float4*)&kg[(size_t)(sb + k_row + 16 * i) * DD + k_f4 * 4];
#pragma unroll
        for (int gi = 0; gi < 2; ++gi) {
            int g = wv + gi * 4;
#pragma unroll
            for (int i = 0; i < 8; ++i)
                vreg[gi][i] = vg[(size_t)(sb + g * 8 + i) * DD + lane];
        }
    }

    for (int t = t0; t < t1; ++t) {
        int s0 = t * 64;
        __syncthreads();
#pragma unroll
        for (int i = 0; i < 4; ++i) {
            float4 f = kreg[i];
            short4v sv;
            sv.x = f2bf(f.x); sv.y = f2bf(f.y); sv.z = f2bf(f.z); sv.w = f2bf(f.w);
            *(short4v*)&k_s[(k_row + 16 * i) * 72 + k_f4 * 4] = sv;
        }
#pragma unroll
        for (int gi = 0; gi < 2; ++gi) {
            int g = wv + gi * 4;
            short8 pk;
#pragma unroll
            for (int i = 0; i < 8; ++i) pk[i] = f2bf(vreg[gi][i]);
            *(short8*)&v_t[lane * 64 + (g ^ (lane & 7)) * 8] = pk;
        }
        __syncthreads();
        if (t + 1 < t1) {
            int sn = s0 + 64;
#pragma unroll
            for (int i = 0; i < 4; ++i)
                kreg[i] = *(const float4*)&kg[(size_t)(sn + k_row + 16 * i) * DD + k_f4 * 4];
#pragma unroll
            for (int gi = 0; gi < 2; ++gi) {
                int g = wv + gi * 4;
#pragma unroll
                for (int i = 0; i < 8; ++i)
                    vreg[gi][i] = vg[(size_t)(sn + g * 8 + i) * DD + lane];
            }
        }

        // ---- scores
        float4v sc[4];
#pragma unroll
        for (int nt = 0; nt < 4; ++nt) {
            const short* kr = &k_s[(nt * 16 + lq) * 72 + quad * 8];
            short8 bk0 = *(const short8*)kr;
            short8 bk1 = *(const short8*)(kr + 32);
            float4v c = (float4v){0.f, 0.f, 0.f, 0.f};
            c = __builtin_amdgcn_mfma_f32_16x16x32_bf16(aq0, bk0, c, 0, 0, 0);
            c = __builtin_amdgcn_mfma_f32_16x16x32_bf16(aq1, bk1, c, 0, 0, 0);
            sc[nt] = c;
        }

        // ---- mask + online softmax (masked = -1e30 -> exp underflows to 0)
        float x[4][4];
#pragma unroll
        for (int nt = 0; nt < 4; ++nt) {
            int s = s0 + nt * 16 + lq;
            int delta = s - end_index;
            int pos = (delta <= 0) ? (last + delta) : (last + delta - CAP);
            if (s >= new_end) pos = -1;
#pragma unroll
            for (int r = 0; r < 4; ++r) {
                int tq = end0 + qc2 * 64 + wv * 16 + quad * 4 + r;
                int dd = tq - pos;
                bool valid = (pos >= 0) && (dd >= 0) && (dd < CAP);
                x[nt][r] = valid ? sc[nt][r] * 0.125f : -1.0e30f;
            }
        }
        float al[4];
#pragma unroll
        for (int r = 0; r < 4; ++r) {
            float vm = fmaxf(fmaxf(x[0][r], x[1][r]), fmaxf(x[2][r], x[3][r]));
            vm = fmaxf(vm, __shfl_xor(vm, 1, 64));
            vm = fmaxf(vm, __shfl_xor(vm, 2, 64));
            vm = fmaxf(vm, __shfl_xor(vm, 4, 64));
            vm = fmaxf(vm, __shfl_xor(vm, 8, 64));
            float mn = fmaxf(m[r], vm);
            al[r] = __expf(m[r] - mn);
            float ps = 0.f;
#pragma unroll
            for (int nt = 0; nt < 4; ++nt) {
                float p = __expf(x[nt][r] - mn);
                x[nt][r] = p;
                ps += p;
            }
            ps += __shfl_xor(ps, 1, 64);
            ps += __shfl_xor(ps, 2, 64);
            ps += __shfl_xor(ps, 4, 64);
            ps += __shfl_xor(ps, 8, 64);
            l[r] = l[r] * al[r] + ps;
            m[r] = mn;
        }
#pragma unroll
        for (int r = 0; r < 4; ++r)
#pragma unroll
            for (int nt = 0; nt < 4; ++nt)
                p_s[wv][(quad * 4 + r) * 72 + nt * 16 + lq] = f2bf(x[nt][r]);
        if (lq == 0) {
#pragma unroll
            for (int r = 0; r < 4; ++r) stat_s[wv][quad * 4 + r] = al[r];
        }

        // ---- PV: O^T += V^T * P^T
        float af = stat_s[wv][lq];
        short8 bp0 = *(const short8*)&p_s[wv][lq * 72 + quad * 8];
        short8 bp1 = *(const short8*)&p_s[wv][lq * 72 + 32 + quad * 8];
#pragma unroll
        for (int mt = 0; mt < 4; ++mt) {
            int d = mt * 16 + lq;
            const short* vr = &v_t[d * 64];
            short8 av0 = *(const short8*)(vr + ((quad ^ (d & 7)) * 8));
            short8 av1 = *(const short8*)(vr + (((4 + quad) ^ (d & 7)) * 8));
            float4v a = acc[mt];
            a.x *= af; a.y *= af; a.z *= af; a.w *= af;
            a = __builtin_amdgcn_mfma_f32_16x16x32_bf16(av0, bp0, a, 0, 0, 0);
            a = __builtin_amdgcn_mfma_f32_16x16x32_bf16(av1, bp1, a, 0, 0, 0);
            acc[mt] = a;
        }
    }

    // ---- epilogue: write unnormalized partials (acc per lane: q=lq, d=mt*16+quad*4+r)
    int base_row = (b * HH + h) * TT + qc2 * 64;
    float* pa = (sid < 3) ? (pacc012 + (size_t)sid * (16384 * 64)) : pacc3;
    int row_g = base_row + wv * 16 + lq;
#pragma unroll
    for (int mt = 0; mt < 4; ++mt)
        *(float4v*)&pa[(size_t)row_g * 64 + mt * 16 + quad * 4] = acc[mt];
    if (lq == 0) {
#pragma unroll
        for (int r = 0; r < 4; ++r) {
            int rg = base_row + wv * 16 + quad * 4 + r;
            size_t ix = ((size_t)sid * 16384 + rg) * 2;
            pml[ix] = m[r];
            pml[ix + 1] = l[r];
        }
    }
}

// ---------------- combine NSPLIT partials; emit fp16 hi/lo for out-proj ----------------
__global__ __launch_bounds__(256) void attn_combine(const float* __restrict__ pacc012,
                                                    const float* __restrict__ pacc3,
                                                    const float* __restrict__ pml,
                                                    _Float16* __restrict__ ahi,
                                                    _Float16* __restrict__ alo) {
    int gid = blockIdx.x * 256 + threadIdx.x;   // 16384 rows x 64 dims
    int row = gid >> 6, d = gid & 63;

    float mv[NSPLIT], lv[NSPLIT];
#pragma unroll
    for (int s = 0; s < NSPLIT; ++s) {
        size_t ix = ((size_t)s * 16384 + row) * 2;
        mv[s] = pml[ix];
        lv[s] = pml[ix + 1];
    }
    float M = fmaxf(fmaxf(mv[0], mv[1]), fmaxf(mv[2], mv[3]));
    float O = 0.f, L = 0.f;
#pragma unroll
    for (int s = 0; s < NSPLIT; ++s) {
        const float* pa = (s < 3) ? (pacc012 + (size_t)s * (16384 * 64)) : pacc3;
        float w = __expf(mv[s] - M);
        L += w * lv[s];
        O += w * pa[(size_t)row * 64 + d];
    }
    float o = (L > 0.f) ? (O / L) : 0.f;

    int b = row >> 11, h = (row >> 7) & 15, q = row & 127;
    size_t ob = ((size_t)(b * TT + q)) * CC + h * DD + d;
    _Float16 hi = (_Float16)o;
    ahi[ob] = hi;
    alo[ob] = (_Float16)(o - (float)hi);
}

extern "C" void kernel_launch(void* const* d_in, const int* in_sizes, int n_in,
                              void* d_out, int out_size, void* d_ws, size_t ws_size,
                              hipStream_t stream) {
    const float* x = (const float*)d_in[0];
    const float* w_in = (const float*)d_in[1];
    const float* w_out = (const float*)d_in[2];
    float* cache_k = (float*)d_in[3];
    float* cache_v = (float*)d_in[4];
    const int* end_offset = (const int*)d_in[5];
    const unsigned char* exec_mask_b = (const unsigned char*)d_in[6];
    const int* exec_mask_i = (const int*)d_in[6];
    float* out = (float*)d_out;

    float* qkv = (float*)d_ws;                                   // 12 MB  [1024][3072] f32
    unsigned short* q_bf = (unsigned short*)(qkv + (size_t)1024 * 3072);  // 2 MB bf16
    _Float16* xhi = (_Float16*)(q_bf + (size_t)1024 * 1024);     // 2 MB each
    _Float16* xlo = xhi + (size_t)1024 * 1024;
    _Float16* wh = xlo + (size_t)1024 * 1024;                    // 6 MB
    _Float16* woh = wh + (size_t)3072 * 1024;                    // 2 MB
    _Float16* ahi = woh + (size_t)1024 * 1024;                   // 2 MB each
    _Float16* alo = ahi + (size_t)1024 * 1024;

    // attention partials alias buffers that are DEAD by the time attn runs:
    //   qkv (12 MB, dead after rope_scatter) -> splits 0..2 (3 x 4 MB, exact fit)
    //   xhi+xlo (4 MB, dead after gemm1)     -> split 3
    //   wh (6 MB, dead after gemm1)          -> m/l pairs (512 KB)
    float* pacc012 = qkv;
    float* pacc3 = (float*)xhi;
    float* pml = (float*)wh;

    // 0) fused split: x -> fp16 hi/lo, weights -> fp16
    split_all<<<5120, 256, 0, stream>>>(x, w_in, w_out, xhi, xlo, wh, woh);
    // 1) QKV projection: [1024,3072] = (xhi+xlo) * wh^T
    gemm_f16x2<2, 4><<<dim3(3072 / 128, 1024 / 64), 256, 0, stream>>>(
        xhi, xlo, wh, qkv, BB * TT, 3 * CC, CC);
    // 2) RoPE + ring scatter
    rope_scatter<<<(BB * TT * HH * 32) / 256, 256, 0, stream>>>(qkv, q_bf, cache_k, cache_v, end_offset);
    // 3) MFMA flash attention, S-split x4 (1024 blocks -> 4 blocks/CU)
    attn_mfma<<<dim3(HH * BB, 2, NSPLIT), 256, 0, stream>>>(q_bf, cache_k, cache_v, end_offset,
                                                            exec_mask_b, exec_mask_i,
                                                            pacc012, pacc3, pml);
    // 3b) combine partials -> fp16 hi/lo for out-proj
    attn_combine<<<(16384 * 64) / 256, 256, 0, stream>>>(pacc012, pacc3, pml, ahi, alo);
    // 4) output projection: [1024,1024] = (ahi+alo) * woh^T
    gemm_f16x2<2, 2><<<dim3(1024 / 64, 1024 / 64), 256, 0, stream>>>(
        ahi, alo, woh, out, BB * TT, CC, CC);
}

// Round 2
// 223.683 us; speedup vs baseline: 1.1354x; 1.0684x over previous
//
#include <hip/hip_runtime.h>
#include <math.h>

// Problem constants (fixed by setup_inputs)
#define BB 8
#define TT 128
#define CC 1024
#define HH 16
#define DD 64
#define CAP 2048
#define NSPLIT 4   // flash-decoding S-splits for attention

typedef __attribute__((ext_vector_type(8))) short short8;
typedef __attribute__((ext_vector_type(4))) short short4v;
typedef __attribute__((ext_vector_type(4))) float float4v;
typedef _Float16 half8 __attribute__((ext_vector_type(8)));
typedef _Float16 half4v __attribute__((ext_vector_type(4)));

__device__ __forceinline__ short f2bf(float x) {
    union { float f; unsigned u; } un; un.f = x;
    unsigned r = (un.u + 0x7FFF + ((un.u >> 16) & 1)) >> 16;
    return (short)r;
}
// packed f32x2 -> bf16x2 (dst low = a, dst high = b); RNE, single instruction
__device__ __forceinline__ unsigned cvt_pk_bf16(float a, float b) {
    unsigned r;
    asm("v_cvt_pk_bf16_f32 %0, %1, %2" : "=v"(r) : "v"(a), "v"(b));
    return r;
}

// ---------------- fused split: x -> fp16 hi/lo; w_in, w_out -> fp16 ----------------
__global__ __launch_bounds__(256) void split_all(const float* __restrict__ x,
                                                 const float* __restrict__ w_in,
                                                 const float* __restrict__ w_out,
                                                 _Float16* __restrict__ xhi,
                                                 _Float16* __restrict__ xlo,
                                                 _Float16* __restrict__ wh,
                                                 _Float16* __restrict__ woh) {
    size_t i = ((size_t)blockIdx.x * 256 + threadIdx.x) * 4;
    if (i < (size_t)1048576) {
        float4 f = *(const float4*)(x + i);
        half4v h, l;
        h.x = (_Float16)f.x; l.x = (_Float16)(f.x - (float)h.x);
        h.y = (_Float16)f.y; l.y = (_Float16)(f.y - (float)h.y);
        h.z = (_Float16)f.z; l.z = (_Float16)(f.z - (float)h.z);
        h.w = (_Float16)f.w; l.w = (_Float16)(f.w - (float)h.w);
        *(half4v*)(xhi + i) = h;
        *(half4v*)(xlo + i) = l;
    } else if (i < (size_t)4194304) {
        size_t off = i - 1048576;
        float4 f = *(const float4*)(w_in + off);
        half4v h;
        h.x = (_Float16)f.x; h.y = (_Float16)f.y; h.z = (_Float16)f.z; h.w = (_Float16)f.w;
        *(half4v*)(wh + off) = h;
    } else {
        size_t off = i - 4194304;
        float4 f = *(const float4*)(w_out + off);
        half4v h;
        h.x = (_Float16)f.x; h.y = (_Float16)f.y; h.z = (_Float16)f.z; h.w = (_Float16)f.w;
        *(half4v*)(woh + off) = h;
    }
}

// ---------------- fp16 2-term GEMM: C[M,N] = (Ahi+Alo)[M,K] * B[N,K]^T ----------------
template <int ROWS>
__device__ __forceinline__ void stage_glds(const unsigned short* __restrict__ src,
                                           unsigned short* lds, int K, int wv, int lane) {
#pragma unroll
    for (int c = wv; c < ROWS / 16; c += 4) {
        int row = c * 16 + (lane >> 2);
        int g = lane & 3;
        const unsigned short* ga = src + (size_t)row * K + g * 8;
        unsigned short* la = lds + c * 512 + lane * 8;
        __builtin_amdgcn_global_load_lds((__attribute__((address_space(1))) const unsigned short*)ga,
                                         (__attribute__((address_space(3))) unsigned short*)la,
                                         16, 0, 0);
    }
}

template <int MT, int NT>
__global__ __launch_bounds__(256) void gemm_f16x2(const _Float16* __restrict__ Ahi,
                                                  const _Float16* __restrict__ Alo,
                                                  const _Float16* __restrict__ Bh,
                                                  float* __restrict__ C, int M, int N, int K) {
    constexpr int BM = 2 * MT * 16, BN = 2 * NT * 16;
    __shared__ __align__(16) _Float16 As_h[BM * 32];
    __shared__ __align__(16) _Float16 As_l[BM * 32];
    __shared__ __align__(16) _Float16 Bs[BN * 32];

    int tid = threadIdx.x;
    int lane = tid & 63, wv = tid >> 6;
    int wr = wv >> 1, wc = wv & 1;
    int quad = lane >> 4, lq = lane & 15;
    int m0 = blockIdx.y * BM, n0 = blockIdx.x * BN;

    float4v acc[MT][NT];
#pragma unroll
    for (int mt = 0; mt < MT; ++mt)
#pragma unroll
        for (int nt = 0; nt < NT; ++nt) acc[mt][nt] = (float4v){0.f, 0.f, 0.f, 0.f};

    const unsigned short* a_h = (const unsigned short*)(Ahi + (size_t)m0 * K);
    const unsigned short* a_l = (const unsigned short*)(Alo + (size_t)m0 * K);
    const unsigned short* b_h = (const unsigned short*)(Bh + (size_t)n0 * K);

    for (int k0 = 0; k0 < K; k0 += 32) {
        __syncthreads();
        stage_glds<BM>(a_h + k0, (unsigned short*)As_h, K, wv, lane);
        stage_glds<BM>(a_l + k0, (unsigned short*)As_l, K, wv, lane);
        stage_glds<BN>(b_h + k0, (unsigned short*)Bs, K, wv, lane);
        __syncthreads();

        half8 ah[MT], al[MT];
#pragma unroll
        for (int mt = 0; mt < MT; ++mt) {
            int row = wr * MT * 16 + mt * 16 + lq;
            ah[mt] = *(const half8*)&As_h[row * 32 + quad * 8];
            al[mt] = *(const half8*)&As_l[row * 32 + quad * 8];
        }
#pragma unroll
        for (int nt = 0; nt < NT; ++nt) {
            int row = wc * NT * 16 + nt * 16 + lq;
            half8 bh = *(const half8*)&Bs[row * 32 + quad * 8];
#pragma unroll
            for (int mt = 0; mt < MT; ++mt) {
                float4v c = acc[mt][nt];
                c = __builtin_amdgcn_mfma_f32_16x16x32_f16(ah[mt], bh, c, 0, 0, 0);
                c = __builtin_amdgcn_mfma_f32_16x16x32_f16(al[mt], bh, c, 0, 0, 0);
                acc[mt][nt] = c;
            }
        }
    }

#pragma unroll
    for (int mt = 0; mt < MT; ++mt)
#pragma unroll
        for (int nt = 0; nt < NT; ++nt) {
            int n = n0 + wc * NT * 16 + nt * 16 + lq;
#pragma unroll
            for (int r = 0; r < 4; ++r) {
                int m = m0 + wr * MT * 16 + mt * 16 + quad * 4 + r;
                C[(size_t)m * N + n] = acc[mt][nt][r];
            }
        }
}

// ---------------- RoPE + ring-buffer scatter; q emitted as bf16 * 0.125 ----------------
__global__ __launch_bounds__(256) void rope_scatter(const float* __restrict__ qkv,
                                                    unsigned short* __restrict__ q_bf,
                                                    float* __restrict__ cache_k,
                                                    float* __restrict__ cache_v,
                                                    const int* __restrict__ end_offset) {
    int gid = blockIdx.x * 256 + threadIdx.x;
    int j = gid & 31;
    int h = (gid >> 5) & 15;
    int t = (gid >> 9) & 127;
    int b = gid >> 16;

    int ts = end_offset[b] + t;
    int slot = ts & (CAP - 1);

    float freq = expf(-0.28782313662425574f * (float)j);
    float ang = (float)ts * freq;
    float s, c;
    sincosf(ang, &s, &c);

    const float* base = qkv + (size_t)(b * TT + t) * (3 * CC);
    int col = h * DD + 2 * j;
    float2 qv = *(const float2*)&base[col];
    float2 kv = *(const float2*)&base[CC + col];
    float2 vv = *(const float2*)&base[2 * CC + col];

    float qr = qv.x * c - qv.y * s;
    float qi = qv.x * s + qv.y * c;
    float kr = kv.x * c - kv.y * s;
    float ki = kv.x * s + kv.y * c;

    size_t qo = ((size_t)(b * HH + h) * TT + t) * DD + 2 * j;
    ushort2 qp;  // fold the 1/sqrt(D)=0.125 attention scale into q (exact in bf16)
    qp.x = (unsigned short)f2bf(qr * 0.125f);
    qp.y = (unsigned short)f2bf(qi * 0.125f);
    *(ushort2*)&q_bf[qo] = qp;
    size_t ko = ((size_t)(b * HH + h) * CAP + slot) * DD + 2 * j;
    *(float2*)&cache_k[ko] = make_float2(kr, ki);
    *(float2*)&cache_v[ko] = vv;
}

// ---------------- MFMA bf16 flash attention, flash-decoding split over S ----------
// Round-2 structure: swapped QK^T (scores [s][q], q lane-local) -> 4 shuffles/tile,
// scalar m/l, lane-local alpha; cvt_pk packing; fast-path unmasked tiles; strided
// sid->tile assignment; flat-id remap so co-resident blocks carry different batches.
__global__ __launch_bounds__(256) void attn_mfma(const unsigned short* __restrict__ qb,
                                                 const float* __restrict__ ck,
                                                 const float* __restrict__ cv,
                                                 const int* __restrict__ endo,
                                                 const unsigned char* __restrict__ emb,
                                                 const int* __restrict__ emi,
                                                 float* __restrict__ pacc012,
                                                 float* __restrict__ pacc3,
                                                 float* __restrict__ pml) {
    __shared__ __align__(16) short k_s[64 * 72];      // [s][d] bf16, stride 72
    __shared__ __align__(16) short v_t[64 * 64];      // [d][s] bf16, XOR-granule swizzle
    __shared__ __align__(16) short p_s[4][16 * 72];   // per-wave P [q][s]

    int tid = threadIdx.x;
    int lane = tid & 63, wv = tid >> 6;
    int quad = lane >> 4, lq = lane & 15;
    // flat remap: sid varies fastest in dispatch order -> the 4 blocks co-resident
    // on one CU carry different (b,h) work instead of the 4 sids of the same range
    int f = blockIdx.x + 128 * (blockIdx.y + 2 * blockIdx.z);
    int sid = f & 3;
    int qc2 = (f >> 2) & 1;
    int hb = f >> 3;
    int h = hb & 15, b = hb >> 4;
    int qrow = qc2 * 64 + wv * 16 + lq;

    int end0 = endo[b];
    int em = (emb[b] != 0) || (emi[b] != 0);
    int last = end0 + TT - 1;
    int end_index = last & (CAP - 1);
    int new_end = em ? (end0 + TT) : end0;
    int se = new_end < CAP ? new_end : CAP;
    int ntiles = (se + 63) >> 6;

    int tq = end0 + qrow;                       // this lane's query position (q = lq)
    int tq0 = end0 + qc2 * 64 + wv * 16;        // wave-min query position
    int len_bad = last - tq0;                   // # cached tokens newer than tq0 (<=127)
    int a_bad = (tq0 + 1) & (CAP - 1);          // first "too new" slot

    const unsigned short* qrp = qb + ((size_t)(b * HH + h) * TT + qrow) * DD;
    short8 aq0 = *(const short8*)(qrp + quad * 8);
    short8 aq1 = *(const short8*)(qrp + 32 + quad * 8);

    const float* kg = ck + (size_t)(b * HH + h) * CAP * DD;
    const float* vg = cv + (size_t)(b * HH + h) * CAP * DD;

    int k_row = tid >> 4, k_f4 = tid & 15;   // K: 4 float4/thread (rows tid>>4 + 16*i)
    float4 kreg[4];
    float vreg[2][8];                        // V: granules {wv, wv+4}, lane = d column

    float m = 0.f, l = 0.f;                  // per-lane (q = lq); max floored at 0
    float4v acc[4];
#pragma unroll
    for (int mt = 0; mt < 4; ++mt) acc[mt] = (float4v){0.f, 0.f, 0.f, 0.f};

    if (sid < ntiles) {
        int sb = sid * 64;
#pragma unroll
        for (int i = 0; i < 4; ++i)
            kreg[i] = *(const float4*)&kg[(size_t)(sb + k_row + 16 * i) * DD + k_f4 * 4];
#pragma unroll
        for (int gi = 0; gi < 2; ++gi) {
            int g = wv + gi * 4;
#pragma unroll
            for (int i = 0; i < 8; ++i)
                vreg[gi][i] = vg[(size_t)(sb + g * 8 + i) * DD + lane];
        }
    }

    for (int t = sid; t < ntiles; t += NSPLIT) {
        int s0 = t * 64;
        __syncthreads();
        // ---- stage K (packed cvt) : 4 x (2 cvt_pk + b64 write)
#pragma unroll
        for (int i = 0; i < 4; ++i) {
            float4 fv = kreg[i];
            uint2 u;
            u.x = cvt_pk_bf16(fv.x, fv.y);
            u.y = cvt_pk_bf16(fv.z, fv.w);
            *(uint2*)&k_s[(k_row + 16 * i) * 72 + k_f4 * 4] = u;
        }
        // ---- stage V transposed: 2 x (4 cvt_pk + b128 write)
#pragma unroll
        for (int gi = 0; gi < 2; ++gi) {
            int g = wv + gi * 4;
            uint4 u;
            u.x = cvt_pk_bf16(vreg[gi][0], vreg[gi][1]);
            u.y = cvt_pk_bf16(vreg[gi][2], vreg[gi][3]);
            u.z = cvt_pk_bf16(vreg[gi][4], vreg[gi][5]);
            u.w = cvt_pk_bf16(vreg[gi][6], vreg[gi][7]);
            *(uint4*)&v_t[lane * 64 + (g ^ (lane & 7)) * 8] = u;
        }
        __syncthreads();
        int tn = t + NSPLIT;
        if (tn < ntiles) {
            int sn = tn * 64;
#pragma unroll
            for (int i = 0; i < 4; ++i)
                kreg[i] = *(const float4*)&kg[(size_t)(sn + k_row + 16 * i) * DD + k_f4 * 4];
#pragma unroll
            for (int gi = 0; gi < 2; ++gi) {
                int g = wv + gi * 4;
#pragma unroll
                for (int i = 0; i < 8; ++i)
                    vreg[gi][i] = vg[(size_t)(sn + g * 8 + i) * DD + lane];
            }
        }

        // ---- scores, swapped operands: D[s][q], q = lq lane-local
        float4v sc[4];
#pragma unroll
        for (int nt = 0; nt < 4; ++nt) {
            const short* kr = &k_s[(nt * 16 + lq) * 72 + quad * 8];
            short8 bk0 = *(const short8*)kr;
            short8 bk1 = *(const short8*)(kr + 32);
            float4v c = (float4v){0.f, 0.f, 0.f, 0.f};
            c = __builtin_amdgcn_mfma_f32_16x16x32_bf16(bk0, aq0, c, 0, 0, 0);
            c = __builtin_amdgcn_mfma_f32_16x16x32_bf16(bk1, aq1, c, 0, 0, 0);
            sc[nt] = c;
        }

        // ---- mask (wave-uniform fast path: tile fully valid for all wave rows)
        int off = (s0 - a_bad) & (CAP - 1);
        bool fast = (off >= len_bad) && (off <= CAP - 64) && (s0 + 63 < se);
        float x[4][4];
        if (fast) {
#pragma unroll
            for (int nt = 0; nt < 4; ++nt)
#pragma unroll
                for (int r = 0; r < 4; ++r) x[nt][r] = sc[nt][r];
        } else {
#pragma unroll
            for (int nt = 0; nt < 4; ++nt)
#pragma unroll
                for (int r = 0; r < 4; ++r) {
                    int s = s0 + nt * 16 + quad * 4 + r;
                    int delta = s - end_index;
                    int pos = (delta <= 0) ? (last + delta) : (last + delta - CAP);
                    bool valid = (s < se) && (pos <= tq);
                    x[nt][r] = valid ? sc[nt][r] : -1.0e30f;
                }
        }

        // ---- online softmax, lane-local q: in-lane 16-max/sum + 2 shuffles each
        float v01 = fmaxf(fmaxf(x[0][0], x[0][1]), fmaxf(x[0][2], x[0][3]));
        float v23 = fmaxf(fmaxf(x[1][0], x[1][1]), fmaxf(x[1][2], x[1][3]));
        float v45 = fmaxf(fmaxf(x[2][0], x[2][1]), fmaxf(x[2][2], x[2][3]));
        float v67 = fmaxf(fmaxf(x[3][0], x[3][1]), fmaxf(x[3][2], x[3][3]));
        float vm = fmaxf(fmaxf(v01, v23), fmaxf(v45, v67));
        vm = fmaxf(vm, __shfl_xor(vm, 16, 64));
        vm = fmaxf(vm, __shfl_xor(vm, 32, 64));
        float mn = fmaxf(m, vm);
        float al = __expf(m - mn);
        float ps = 0.f;
#pragma unroll
        for (int nt = 0; nt < 4; ++nt)
#pragma unroll
            for (int r = 0; r < 4; ++r) {
                float p = __expf(x[nt][r] - mn);
                x[nt][r] = p;
                ps += p;
            }
        ps += __shfl_xor(ps, 16, 64);
        ps += __shfl_xor(ps, 32, 64);
        l = l * al + ps;
        m = mn;

        // ---- P store: packed rows [q=lq][s], 4 x b64
#pragma unroll
        for (int nt = 0; nt < 4; ++nt) {
            uint2 u;
            u.x = cvt_pk_bf16(x[nt][0], x[nt][1]);
            u.y = cvt_pk_bf16(x[nt][2], x[nt][3]);
            *(uint2*)&p_s[wv][lq * 72 + nt * 16 + quad * 4] = u;
        }

        // ---- PV: O^T += V^T * P^T  (alpha lane-local)
        short8 bp0 = *(const short8*)&p_s[wv][lq * 72 + quad * 8];
        short8 bp1 = *(const short8*)&p_s[wv][lq * 72 + 32 + quad * 8];
#pragma unroll
        for (int mt = 0; mt < 4; ++mt) {
            int d = mt * 16 + lq;
            const short* vr = &v_t[d * 64];
            short8 av0 = *(const short8*)(vr + ((quad ^ (d & 7)) * 8));
            short8 av1 = *(const short8*)(vr + (((4 + quad) ^ (d & 7)) * 8));
            float4v a = acc[mt];
            a.x *= al; a.y *= al; a.z *= al; a.w *= al;
            a = __builtin_amdgcn_mfma_f32_16x16x32_bf16(av0, bp0, a, 0, 0, 0);
            a = __builtin_amdgcn_mfma_f32_16x16x32_bf16(av1, bp1, a, 0, 0, 0);
            acc[mt] = a;
        }
    }

    // ---- epilogue: write unnormalized partials (acc: q=lq, d=mt*16+quad*4+r)
    int base_row = (b * HH + h) * TT + qc2 * 64;
    float* pa = (sid < 3) ? (pacc012 + (size_t)sid * (16384 * 64)) : pacc3;
    int row_g = base_row + wv * 16 + lq;
#pragma unroll
    for (int mt = 0; mt < 4; ++mt)
        *(float4v*)&pa[(size_t)row_g * 64 + mt * 16 + quad * 4] = acc[mt];
    if (quad == 0) {
        size_t ix = ((size_t)sid * 16384 + row_g) * 2;
        pml[ix] = m;
        pml[ix + 1] = l;
    }
}

// ---------------- combine NSPLIT partials; emit fp16 hi/lo for out-proj ----------------
__global__ __launch_bounds__(256) void attn_combine(const float* __restrict__ pacc012,
                                                    const float* __restrict__ pacc3,
                                                    const float* __restrict__ pml,
                                                    _Float16* __restrict__ ahi,
                                                    _Float16* __restrict__ alo) {
    int gid = blockIdx.x * 256 + threadIdx.x;   // 16384 rows x 64 dims
    int row = gid >> 6, d = gid & 63;

    float mv[NSPLIT], lv[NSPLIT];
#pragma unroll
    for (int s = 0; s < NSPLIT; ++s) {
        size_t ix = ((size_t)s * 16384 + row) * 2;
        mv[s] = pml[ix];
        lv[s] = pml[ix + 1];
    }
    float M = fmaxf(fmaxf(mv[0], mv[1]), fmaxf(mv[2], mv[3]));
    float O = 0.f, L = 0.f;
#pragma unroll
    for (int s = 0; s < NSPLIT; ++s) {
        const float* pa = (s < 3) ? (pacc012 + (size_t)s * (16384 * 64)) : pacc3;
        float w = __expf(mv[s] - M);
        L += w * lv[s];
        O += w * pa[(size_t)row * 64 + d];
    }
    float o = (L > 0.f) ? (O / L) : 0.f;

    int b = row >> 11, h = (row >> 7) & 15, q = row & 127;
    size_t ob = ((size_t)(b * TT + q)) * CC + h * DD + d;
    _Float16 hi = (_Float16)o;
    ahi[ob] = hi;
    alo[ob] = (_Float16)(o - (float)hi);
}

extern "C" void kernel_launch(void* const* d_in, const int* in_sizes, int n_in,
                              void* d_out, int out_size, void* d_ws, size_t ws_size,
                              hipStream_t stream) {
    const float* x = (const float*)d_in[0];
    const float* w_in = (const float*)d_in[1];
    const float* w_out = (const float*)d_in[2];
    float* cache_k = (float*)d_in[3];
    float* cache_v = (float*)d_in[4];
    const int* end_offset = (const int*)d_in[5];
    const unsigned char* exec_mask_b = (const unsigned char*)d_in[6];
    const int* exec_mask_i = (const int*)d_in[6];
    float* out = (float*)d_out;

    float* qkv = (float*)d_ws;                                   // 12 MB  [1024][3072] f32
    unsigned short* q_bf = (unsigned short*)(qkv + (size_t)1024 * 3072);  // 2 MB bf16
    _Float16* xhi = (_Float16*)(q_bf + (size_t)1024 * 1024);     // 2 MB each
    _Float16* xlo = xhi + (size_t)1024 * 1024;
    _Float16* wh = xlo + (size_t)1024 * 1024;                    // 6 MB
    _Float16* woh = wh + (size_t)3072 * 1024;                    // 2 MB
    _Float16* ahi = woh + (size_t)1024 * 1024;                   // 2 MB each
    _Float16* alo = ahi + (size_t)1024 * 1024;

    // attention partials alias buffers that are DEAD by the time attn runs:
    //   qkv (12 MB, dead after rope_scatter) -> splits 0..2 (3 x 4 MB, exact fit)
    //   xhi+xlo (4 MB, dead after gemm1)     -> split 3
    //   wh (6 MB, dead after gemm1)          -> m/l pairs (512 KB)
    float* pacc012 = qkv;
    float* pacc3 = (float*)xhi;
    float* pml = (float*)wh;

    // 0) fused split: x -> fp16 hi/lo, weights -> fp16
    split_all<<<5120, 256, 0, stream>>>(x, w_in, w_out, xhi, xlo, wh, woh);
    // 1) QKV projection: [1024,3072] = (xhi+xlo) * wh^T (BM=64,BN=64 -> 768 blocks, 3/CU)
    gemm_f16x2<2, 2><<<dim3(3072 / 64, 1024 / 64), 256, 0, stream>>>(
        xhi, xlo, wh, qkv, BB * TT, 3 * CC, CC);
    // 2) RoPE + ring scatter (q pre-scaled by 0.125)
    rope_scatter<<<(BB * TT * HH * 32) / 256, 256, 0, stream>>>(qkv, q_bf, cache_k, cache_v, end_offset);
    // 3) MFMA flash attention, S-split x4 (1024 blocks, flat-remapped for balance)
    attn_mfma<<<dim3(HH * BB, 2, NSPLIT), 256, 0, stream>>>(q_bf, cache_k, cache_v, end_offset,
                                                            exec_mask_b, exec_mask_i,
                                                            pacc012, pacc3, pml);
    // 3b) combine partials -> fp16 hi/lo for out-proj
    attn_combine<<<(16384 * 64) / 256, 256, 0, stream>>>(pacc012, pacc3, pml, ahi, alo);
    // 4) output projection: [1024,1024] = (ahi+alo) * woh^T (BM=32,BN=64 -> 512 blocks, 2/CU)
    gemm_f16x2<1, 2><<<dim3(1024 / 64, 1024 / 32), 256, 0, stream>>>(
        ahi, alo, woh, out, BB * TT, CC, CC);
}